// Round 1
// baseline (350.918 us; speedup 1.0000x reference)
//
#include <hip/hip_runtime.h>
#include <math.h>

#define Bb 4
#define Rr 512
#define Ccc 512
#define Hh 8
#define Dd 64
#define Ee 512
#define HMS 128

// ---------------------------------------------------------------------------
// GEMM: C[M][512] = A[M][512] @ Bw[512][512]^T   (Bw row-major [N][K])
// 64x64 tile, BK=16, 256 threads, 4x4 microtile.
// ---------------------------------------------------------------------------
__global__ __launch_bounds__(256) void gemm_abt(const float* __restrict__ A,
                                                const float* __restrict__ Bw,
                                                float* __restrict__ C) {
    __shared__ float As[16][64];
    __shared__ float Bs[16][64];
    const int t  = threadIdx.x;
    const int tm = t / 16, tn = t % 16;
    const int m0 = blockIdx.x * 64;
    const int n0 = blockIdx.y * 64;

    float acc[4][4] = {};

    for (int k0 = 0; k0 < 512; k0 += 16) {
        {
            const int row = t / 4;   // 0..63
            const int c4  = t % 4;   // 0..3
            const float4 av = *(const float4*)(A  + (size_t)(m0 + row) * 512 + k0 + c4 * 4);
            As[c4 * 4 + 0][row] = av.x;
            As[c4 * 4 + 1][row] = av.y;
            As[c4 * 4 + 2][row] = av.z;
            As[c4 * 4 + 3][row] = av.w;
            const float4 bv = *(const float4*)(Bw + (size_t)(n0 + row) * 512 + k0 + c4 * 4);
            Bs[c4 * 4 + 0][row] = bv.x;
            Bs[c4 * 4 + 1][row] = bv.y;
            Bs[c4 * 4 + 2][row] = bv.z;
            Bs[c4 * 4 + 3][row] = bv.w;
        }
        __syncthreads();
#pragma unroll
        for (int k = 0; k < 16; ++k) {
            const float4 a = *(const float4*)&As[k][tm * 4];
            const float4 b = *(const float4*)&Bs[k][tn * 4];
            acc[0][0] += a.x * b.x; acc[0][1] += a.x * b.y; acc[0][2] += a.x * b.z; acc[0][3] += a.x * b.w;
            acc[1][0] += a.y * b.x; acc[1][1] += a.y * b.y; acc[1][2] += a.y * b.z; acc[1][3] += a.y * b.w;
            acc[2][0] += a.z * b.x; acc[2][1] += a.z * b.y; acc[2][2] += a.z * b.z; acc[2][3] += a.z * b.w;
            acc[3][0] += a.w * b.x; acc[3][1] += a.w * b.y; acc[3][2] += a.w * b.z; acc[3][3] += a.w * b.w;
        }
        __syncthreads();
    }
#pragma unroll
    for (int i = 0; i < 4; ++i)
#pragma unroll
        for (int j = 0; j < 4; ++j)
            C[(size_t)(m0 + tm * 4 + i) * 512 + n0 + tn * 4 + j] = acc[i][j];
}

// ---------------------------------------------------------------------------
// dot + mixing MLP fused.
// grid: (cTiles=16, rTiles=16, b=4), 256 threads. Tile = 32 rows x 32 cols.
// Computes dot[h][32][32] for all 8 heads into LDS, then per-cell MLP,
// writes logits[b][h][r][c] (fp32).
// ---------------------------------------------------------------------------
__global__ __launch_bounds__(256) void dot_mlp(const float* __restrict__ Q,
                                               const float* __restrict__ K,
                                               const float* __restrict__ cost,
                                               const float* __restrict__ W1,
                                               const float* __restrict__ W2,
                                               float* __restrict__ logits) {
    __shared__ float qs[32][68];      // padded: +4 floats to break bank conflicts
    __shared__ float ks[32][68];
    __shared__ float dotL[8][32][32];
    __shared__ float A1s[128][8];
    __shared__ float bcs[128];
    __shared__ float W2t[128][8];

    const int b  = blockIdx.z;
    const int r0 = blockIdx.y * 32;
    const int c0 = blockIdx.x * 32;
    const int t  = threadIdx.x;

    // stage folded MLP weights
    if (t < 128) {
        const int j = t;
        float bc = 0.f;
#pragma unroll
        for (int h = 0; h < 8; ++h) {
            A1s[j][h] = W1[j * 16 + 2 * h];
            bc       += W1[j * 16 + 2 * h + 1];
            W2t[j][h] = W2[h * 128 + j];
        }
        bcs[j] = bc;
    }

    const int ty = t / 16, tx = t % 16;
    const int rr = ty * 2, cc = tx * 2;

    for (int h = 0; h < 8; ++h) {
#pragma unroll
        for (int i = 0; i < 2; ++i) {
            const int idx = t + i * 256;   // 0..511
            const int row = idx / 16;      // 0..31
            const int c4  = idx % 16;      // 0..15
            *(float4*)&qs[row][c4 * 4] =
                *(const float4*)(Q + ((size_t)b * 512 + r0 + row) * 512 + h * 64 + c4 * 4);
            *(float4*)&ks[row][c4 * 4] =
                *(const float4*)(K + ((size_t)b * 512 + c0 + row) * 512 + h * 64 + c4 * 4);
        }
        __syncthreads();
        float a00 = 0.f, a01 = 0.f, a10 = 0.f, a11 = 0.f;
#pragma unroll
        for (int d4 = 0; d4 < 16; ++d4) {
            const float4 q0 = *(const float4*)&qs[rr][d4 * 4];
            const float4 q1 = *(const float4*)&qs[rr + 1][d4 * 4];
            const float4 k0 = *(const float4*)&ks[cc][d4 * 4];
            const float4 k1 = *(const float4*)&ks[cc + 1][d4 * 4];
            a00 += q0.x * k0.x + q0.y * k0.y + q0.z * k0.z + q0.w * k0.w;
            a01 += q0.x * k1.x + q0.y * k1.y + q0.z * k1.z + q0.w * k1.w;
            a10 += q1.x * k0.x + q1.y * k0.y + q1.z * k0.z + q1.w * k0.w;
            a11 += q1.x * k1.x + q1.y * k1.y + q1.z * k1.z + q1.w * k1.w;
        }
        const float norm = 0.125f;  // 1/sqrt(64)
        dotL[h][rr][cc]         = a00 * norm;
        dotL[h][rr][cc + 1]     = a01 * norm;
        dotL[h][rr + 1][cc]     = a10 * norm;
        dotL[h][rr + 1][cc + 1] = a11 * norm;
        __syncthreads();
    }

    // MLP phase: 4 cells per thread
    float dreg[4][8];
    float costr[4];
    float ms[4][8] = {};
#pragma unroll
    for (int cell = 0; cell < 4; ++cell) {
        const int id  = t + cell * 256;
        const int row = id / 32, col = id % 32;
#pragma unroll
        for (int h = 0; h < 8; ++h) dreg[cell][h] = dotL[h][row][col];
        costr[cell] = cost[((size_t)b * 512 + r0 + row) * 512 + c0 + col];
    }

    for (int j = 0; j < 128; ++j) {
        const float4 a0 = *(const float4*)&A1s[j][0];
        const float4 a1 = *(const float4*)&A1s[j][4];
        const float  bc = bcs[j];
        const float4 w0 = *(const float4*)&W2t[j][0];
        const float4 w1 = *(const float4*)&W2t[j][4];
#pragma unroll
        for (int cell = 0; cell < 4; ++cell) {
            float pre = bc * costr[cell];
            pre += a0.x * dreg[cell][0] + a0.y * dreg[cell][1] +
                   a0.z * dreg[cell][2] + a0.w * dreg[cell][3];
            pre += a1.x * dreg[cell][4] + a1.y * dreg[cell][5] +
                   a1.z * dreg[cell][6] + a1.w * dreg[cell][7];
            pre = fmaxf(pre, 0.f);
            ms[cell][0] += w0.x * pre; ms[cell][1] += w0.y * pre;
            ms[cell][2] += w0.z * pre; ms[cell][3] += w0.w * pre;
            ms[cell][4] += w1.x * pre; ms[cell][5] += w1.y * pre;
            ms[cell][6] += w1.z * pre; ms[cell][7] += w1.w * pre;
        }
    }

#pragma unroll
    for (int cell = 0; cell < 4; ++cell) {
        const int id  = t + cell * 256;
        const int row = id / 32, col = id % 32;
#pragma unroll
        for (int h = 0; h < 8; ++h) {
            logits[(((size_t)(b * 8 + h)) * 512 + r0 + row) * 512 + c0 + col] = ms[cell][h];
        }
    }
}

// ---------------------------------------------------------------------------
// Masked softmax over c (in-place on logits). One wave per row; 4 rows/block.
// all-masked rows become fully unmasked (reference semantics).
// ---------------------------------------------------------------------------
__global__ __launch_bounds__(256) void softmax_mask(float* __restrict__ logits,
                                                    const int* __restrict__ mask) {
    const int wave = threadIdx.x / 64;
    const int lane = threadIdx.x % 64;
    const size_t rowIdx = (size_t)blockIdx.x * 4 + wave;  // 0..16383
    float* lp = logits + rowIdx * 512;
    const int* mp = mask + rowIdx * 512;

    float v[8];
    int   m[8];
    int allm = 1;
#pragma unroll
    for (int i = 0; i < 8; ++i) {
        v[i] = lp[lane + i * 64];
        m[i] = mp[lane + i * 64];
        allm &= (m[i] != 0);
    }
    const bool all_masked = (__all(allm) != 0);

    float mx = -__builtin_inff();
#pragma unroll
    for (int i = 0; i < 8; ++i) {
        const bool keep = all_masked || (m[i] == 0);
        if (keep) mx = fmaxf(mx, v[i]);
    }
#pragma unroll
    for (int s = 32; s > 0; s >>= 1) mx = fmaxf(mx, __shfl_xor(mx, s, 64));

    float e[8];
    float sum = 0.f;
#pragma unroll
    for (int i = 0; i < 8; ++i) {
        const bool keep = all_masked || (m[i] == 0);
        e[i] = keep ? __expf(v[i] - mx) : 0.f;
        sum += e[i];
    }
#pragma unroll
    for (int s = 32; s > 0; s >>= 1) sum += __shfl_xor(sum, s, 64);

    const float inv = 1.f / sum;
#pragma unroll
    for (int i = 0; i < 8; ++i) lp[lane + i * 64] = e[i] * inv;
}

// ---------------------------------------------------------------------------
// PV: per (b,h): Aout[b][r][h*64+d] = sum_c weights[b][h][r][c] * V[b][c][h*64+d]
// grid: (rTiles=8, b*H=32), 256 threads, 64x64 tile, BK=16.
// ---------------------------------------------------------------------------
__global__ __launch_bounds__(256) void pv_gemm(const float* __restrict__ Wt,
                                               const float* __restrict__ V,
                                               float* __restrict__ Aout) {
    __shared__ float Ws[16][64];
    __shared__ float Vs[16][64];
    const int bh = blockIdx.y;
    const int b = bh / 8, h = bh % 8;
    const int r0 = blockIdx.x * 64;
    const int t  = threadIdx.x;
    const int tm = t / 16, tn = t % 16;

    const float* wbase = Wt + ((size_t)bh) * 512 * 512;
    const float* vbase = V + (size_t)b * 512 * 512 + h * 64;

    float acc[4][4] = {};

    for (int c0 = 0; c0 < 512; c0 += 16) {
        {
            const int row = t / 4, c4 = t % 4;
            const float4 wv = *(const float4*)(wbase + (size_t)(r0 + row) * 512 + c0 + c4 * 4);
            Ws[c4 * 4 + 0][row] = wv.x;
            Ws[c4 * 4 + 1][row] = wv.y;
            Ws[c4 * 4 + 2][row] = wv.z;
            Ws[c4 * 4 + 3][row] = wv.w;
            const int vrow = t / 16, vc4 = t % 16;
            *(float4*)&Vs[vrow][vc4 * 4] =
                *(const float4*)(vbase + (size_t)(c0 + vrow) * 512 + vc4 * 4);
        }
        __syncthreads();
#pragma unroll
        for (int k = 0; k < 16; ++k) {
            const float4 a = *(const float4*)&Ws[k][tm * 4];
            const float4 bb = *(const float4*)&Vs[k][tn * 4];
            acc[0][0] += a.x * bb.x; acc[0][1] += a.x * bb.y; acc[0][2] += a.x * bb.z; acc[0][3] += a.x * bb.w;
            acc[1][0] += a.y * bb.x; acc[1][1] += a.y * bb.y; acc[1][2] += a.y * bb.z; acc[1][3] += a.y * bb.w;
            acc[2][0] += a.z * bb.x; acc[2][1] += a.z * bb.y; acc[2][2] += a.z * bb.z; acc[2][3] += a.z * bb.w;
            acc[3][0] += a.w * bb.x; acc[3][1] += a.w * bb.y; acc[3][2] += a.w * bb.z; acc[3][3] += a.w * bb.w;
        }
        __syncthreads();
    }
#pragma unroll
    for (int i = 0; i < 4; ++i)
#pragma unroll
        for (int j = 0; j < 4; ++j)
            Aout[((size_t)b * 512 + r0 + tm * 4 + i) * 512 + h * 64 + tn * 4 + j] = acc[i][j];
}

// ---------------------------------------------------------------------------
extern "C" void kernel_launch(void* const* d_in, const int* in_sizes, int n_in,
                              void* d_out, int out_size, void* d_ws, size_t ws_size,
                              hipStream_t stream) {
    const float* row_emb = (const float*)d_in[0];
    const float* col_emb = (const float*)d_in[1];
    const float* cost    = (const float*)d_in[2];
    const int*   mask    = (const int*)d_in[3];
    const float* Wq      = (const float*)d_in[4];
    const float* Wk      = (const float*)d_in[5];
    const float* Wv      = (const float*)d_in[6];
    const float* Wmix1   = (const float*)d_in[7];
    const float* Wmix2   = (const float*)d_in[8];
    const float* Wout    = (const float*)d_in[9];
    float* out = (float*)d_out;

    char* ws = (char*)d_ws;
    float* Q      = (float*)(ws);                       // 4 MB  [b][r][h*64+d]
    float* Kp     = (float*)(ws + ((size_t)4  << 20));  // 4 MB  [b][c][h*64+d]
    float* V      = (float*)(ws + ((size_t)8  << 20));  // 4 MB  [b][c][h*64+d]
    float* Aout   = (float*)(ws + ((size_t)12 << 20));  // 4 MB  [b][r][h*64+d]
    float* logitsBuf = (float*)(ws + ((size_t)16 << 20)); // 128 MB [b][h][r][c]

    dim3 g1(2048 / 64, 512 / 64);   // (32, 8)
    gemm_abt<<<g1, 256, 0, stream>>>(row_emb, Wq, Q);
    gemm_abt<<<g1, 256, 0, stream>>>(col_emb, Wk, Kp);
    gemm_abt<<<g1, 256, 0, stream>>>(col_emb, Wv, V);

    dim3 g2(16, 16, 4);
    dot_mlp<<<g2, 256, 0, stream>>>(Q, Kp, cost, Wmix1, Wmix2, logitsBuf);

    softmax_mask<<<4096, 256, 0, stream>>>(logitsBuf, mask);

    dim3 g4(8, 32);
    pv_gemm<<<g4, 256, 0, stream>>>(logitsBuf, V, Aout);

    gemm_abt<<<g1, 256, 0, stream>>>(Aout, Wout, out);
}

// Round 2
// 296.739 us; speedup vs baseline: 1.1826x; 1.1826x over previous
//
#include <hip/hip_runtime.h>
#include <math.h>

typedef __attribute__((ext_vector_type(8))) short bf16x8;
typedef __attribute__((ext_vector_type(4))) float f32x4;

static __device__ inline unsigned short f2bf(float f) {
    union { float f; unsigned u; } v; v.f = f;
    unsigned r = v.u + 0x7fff + ((v.u >> 16) & 1);
    return (unsigned short)(r >> 16);
}

// ---------------------------------------------------------------------------
// GEMM: C[M][512] = A[M][512] @ Bw[512][512]^T   fp32 compute, fp32 out
// ---------------------------------------------------------------------------
__global__ __launch_bounds__(256) void gemm_abt(const float* __restrict__ A,
                                                const float* __restrict__ Bw,
                                                float* __restrict__ C) {
    __shared__ float As[16][64];
    __shared__ float Bs[16][64];
    const int t  = threadIdx.x;
    const int tm = t / 16, tn = t % 16;
    const int m0 = blockIdx.x * 64;
    const int n0 = blockIdx.y * 64;

    float acc[4][4] = {};

    for (int k0 = 0; k0 < 512; k0 += 16) {
        {
            const int row = t / 4;
            const int c4  = t % 4;
            const float4 av = *(const float4*)(A  + (size_t)(m0 + row) * 512 + k0 + c4 * 4);
            As[c4 * 4 + 0][row] = av.x;
            As[c4 * 4 + 1][row] = av.y;
            As[c4 * 4 + 2][row] = av.z;
            As[c4 * 4 + 3][row] = av.w;
            const float4 bv = *(const float4*)(Bw + (size_t)(n0 + row) * 512 + k0 + c4 * 4);
            Bs[c4 * 4 + 0][row] = bv.x;
            Bs[c4 * 4 + 1][row] = bv.y;
            Bs[c4 * 4 + 2][row] = bv.z;
            Bs[c4 * 4 + 3][row] = bv.w;
        }
        __syncthreads();
#pragma unroll
        for (int k = 0; k < 16; ++k) {
            const float4 a = *(const float4*)&As[k][tm * 4];
            const float4 b = *(const float4*)&Bs[k][tn * 4];
            acc[0][0] += a.x * b.x; acc[0][1] += a.x * b.y; acc[0][2] += a.x * b.z; acc[0][3] += a.x * b.w;
            acc[1][0] += a.y * b.x; acc[1][1] += a.y * b.y; acc[1][2] += a.y * b.z; acc[1][3] += a.y * b.w;
            acc[2][0] += a.z * b.x; acc[2][1] += a.z * b.y; acc[2][2] += a.z * b.z; acc[2][3] += a.z * b.w;
            acc[3][0] += a.w * b.x; acc[3][1] += a.w * b.y; acc[3][2] += a.w * b.z; acc[3][3] += a.w * b.w;
        }
        __syncthreads();
    }
#pragma unroll
    for (int i = 0; i < 4; ++i)
#pragma unroll
        for (int j = 0; j < 4; ++j)
            C[(size_t)(m0 + tm * 4 + i) * 512 + n0 + tn * 4 + j] = acc[i][j];
}

// Same GEMM but stores bf16 (for Q, K feeding the MFMA dot kernel).
__global__ __launch_bounds__(256) void gemm_abt_bf16(const float* __restrict__ A,
                                                     const float* __restrict__ Bw,
                                                     unsigned short* __restrict__ Cb) {
    __shared__ float As[16][64];
    __shared__ float Bs[16][64];
    const int t  = threadIdx.x;
    const int tm = t / 16, tn = t % 16;
    const int m0 = blockIdx.x * 64;
    const int n0 = blockIdx.y * 64;

    float acc[4][4] = {};

    for (int k0 = 0; k0 < 512; k0 += 16) {
        {
            const int row = t / 4;
            const int c4  = t % 4;
            const float4 av = *(const float4*)(A  + (size_t)(m0 + row) * 512 + k0 + c4 * 4);
            As[c4 * 4 + 0][row] = av.x;
            As[c4 * 4 + 1][row] = av.y;
            As[c4 * 4 + 2][row] = av.z;
            As[c4 * 4 + 3][row] = av.w;
            const float4 bv = *(const float4*)(Bw + (size_t)(n0 + row) * 512 + k0 + c4 * 4);
            Bs[c4 * 4 + 0][row] = bv.x;
            Bs[c4 * 4 + 1][row] = bv.y;
            Bs[c4 * 4 + 2][row] = bv.z;
            Bs[c4 * 4 + 3][row] = bv.w;
        }
        __syncthreads();
#pragma unroll
        for (int k = 0; k < 16; ++k) {
            const float4 a = *(const float4*)&As[k][tm * 4];
            const float4 b = *(const float4*)&Bs[k][tn * 4];
            acc[0][0] += a.x * b.x; acc[0][1] += a.x * b.y; acc[0][2] += a.x * b.z; acc[0][3] += a.x * b.w;
            acc[1][0] += a.y * b.x; acc[1][1] += a.y * b.y; acc[1][2] += a.y * b.z; acc[1][3] += a.y * b.w;
            acc[2][0] += a.z * b.x; acc[2][1] += a.z * b.y; acc[2][2] += a.z * b.z; acc[2][3] += a.z * b.w;
            acc[3][0] += a.w * b.x; acc[3][1] += a.w * b.y; acc[3][2] += a.w * b.z; acc[3][3] += a.w * b.w;
        }
        __syncthreads();
    }
#pragma unroll
    for (int i = 0; i < 4; ++i) {
        ushort4 o;
        o.x = f2bf(acc[i][0]); o.y = f2bf(acc[i][1]);
        o.z = f2bf(acc[i][2]); o.w = f2bf(acc[i][3]);
        *(ushort4*)&Cb[(size_t)(m0 + tm * 4 + i) * 512 + n0 + tn * 4] = o;
    }
}

// ---------------------------------------------------------------------------
// dot + mixing MLP, MFMA version.
// grid: (16,16,4), 256 threads (4 waves). Tile = 32r x 32c = 1024 cells.
// Phase A: QK^T dots (8 heads) via mfma 16x16x32 bf16, frags loaded straight
//          from global bf16 Q/K; packed bf16 writes into LDS X[cell][16]
//          (folded layout: X[0..7]=dot_h*norm, X[8]=cost, X[9..15]=0).
// Phase B: per-wave: layer1 mfma (K=16 zero-padded to 32) -> relu ->
//          per-wave-private LDS transpose -> layer2 mfma (K=128, N=8 padded).
// ---------------------------------------------------------------------------
__global__ __launch_bounds__(256) void dot_mlp_mfma(const unsigned short* __restrict__ Qb,
                                                    const unsigned short* __restrict__ Kb,
                                                    const float* __restrict__ cost,
                                                    const float* __restrict__ W1,
                                                    const float* __restrict__ W2,
                                                    float* __restrict__ logits) {
    __shared__ unsigned short Xs[1024 * 16];    // 32 KB
    __shared__ unsigned short hidS[4 * 16 * 128]; // 16 KB (per-wave private 4 KB)
    __shared__ unsigned short W1fs[128 * 16];   // 4 KB
    __shared__ unsigned short W2ss[8 * 128];    // 2 KB

    const int b  = blockIdx.z;
    const int r0 = blockIdx.y * 32;
    const int c0 = blockIdx.x * 32;
    const int t    = threadIdx.x;
    const int w    = t >> 6;
    const int lane = t & 63;
    const int quad = lane >> 4;
    const int sl   = lane & 15;

    const bf16x8 zf = {0, 0, 0, 0, 0, 0, 0, 0};

    // --- stage folded W1 (bf16) and W2 (bf16) ---
    if (t < 128) {
        float s = 0.f;
#pragma unroll
        for (int h = 0; h < 8; ++h) {
            W1fs[t * 16 + h] = f2bf(W1[t * 16 + 2 * h]);
            s += W1[t * 16 + 2 * h + 1];
        }
        W1fs[t * 16 + 8] = f2bf(s);
#pragma unroll
        for (int k = 9; k < 16; ++k) W1fs[t * 16 + k] = 0;
    }
#pragma unroll
    for (int i = 0; i < 4; ++i) {
        const int idx = t + i * 256;  // 0..1023
        W2ss[idx] = f2bf(W2[idx]);
    }

    // --- cost -> X[cell][8], zeros X[cell][9..15] ---
#pragma unroll
    for (int i = 0; i < 4; ++i) {
        const int cell = t + i * 256;
        const int rl = cell >> 5, cl = cell & 31;
        const float cv = cost[((size_t)b * 512 + r0 + rl) * 512 + c0 + cl];
        bf16x8 cf = zf;
        cf[0] = (short)f2bf(cv);
        *(bf16x8*)&Xs[cell * 16 + 8] = cf;
    }

    // --- Phase A: dots for heads 2w, 2w+1 ---
    f32x4 dacc[2][2][2];
#pragma unroll
    for (int hh = 0; hh < 2; ++hh) {
        const int h = 2 * w + hh;
        bf16x8 af[2][2], bfr[2][2];
#pragma unroll
        for (int rs = 0; rs < 2; ++rs)
#pragma unroll
            for (int ks = 0; ks < 2; ++ks)
                af[rs][ks] = *(const bf16x8*)(Qb +
                    ((size_t)(b * 512 + r0 + rs * 16 + sl) * 512 + h * 64 + ks * 32 + quad * 8));
#pragma unroll
        for (int cs = 0; cs < 2; ++cs)
#pragma unroll
            for (int ks = 0; ks < 2; ++ks)
                bfr[cs][ks] = *(const bf16x8*)(Kb +
                    ((size_t)(b * 512 + c0 + cs * 16 + sl) * 512 + h * 64 + ks * 32 + quad * 8));
#pragma unroll
        for (int rs = 0; rs < 2; ++rs)
#pragma unroll
            for (int cs = 0; cs < 2; ++cs) {
                f32x4 acc = {0.f, 0.f, 0.f, 0.f};
                acc = __builtin_amdgcn_mfma_f32_16x16x32_bf16(af[rs][0], bfr[cs][0], acc, 0, 0, 0);
                acc = __builtin_amdgcn_mfma_f32_16x16x32_bf16(af[rs][1], bfr[cs][1], acc, 0, 0, 0);
                dacc[hh][rs][cs] = acc;
            }
    }
    // write packed (2 heads -> one dword at dword-offset w of X row)
#pragma unroll
    for (int rs = 0; rs < 2; ++rs)
#pragma unroll
        for (int cs = 0; cs < 2; ++cs)
#pragma unroll
            for (int reg = 0; reg < 4; ++reg) {
                const int cell = (rs * 16 + quad * 4 + reg) * 32 + cs * 16 + sl;
                const unsigned lo = f2bf(dacc[0][rs][cs][reg] * 0.125f);
                const unsigned hi = f2bf(dacc[1][rs][cs][reg] * 0.125f);
                ((unsigned*)Xs)[cell * 8 + w] = lo | (hi << 16);
            }

    __syncthreads();

    // --- Phase B: MLP ---
    // preload B-frags for layer1 (8 n-tiles) and layer2 (4 k-steps)
    bf16x8 bw1[8];
#pragma unroll
    for (int nt = 0; nt < 8; ++nt)
        bw1[nt] = (quad < 2) ? *(const bf16x8*)&W1fs[(nt * 16 + sl) * 16 + quad * 8] : zf;
    bf16x8 bw2[4];
#pragma unroll
    for (int ks = 0; ks < 4; ++ks)
        bw2[ks] = (sl < 8) ? *(const bf16x8*)&W2ss[sl * 128 + ks * 32 + quad * 8] : zf;

    unsigned short* hidW = &hidS[w * 2048];

    for (int mt = 0; mt < 16; ++mt) {
        const int gmt = w * 16 + mt;       // global m-tile 0..63
        const int cb  = gmt * 16;          // cell base

        // layer 1
        const bf16x8 a1 = (quad < 2) ? *(const bf16x8*)&Xs[(cb + sl) * 16 + quad * 8] : zf;
        f32x4 hacc[8];
#pragma unroll
        for (int nt = 0; nt < 8; ++nt) {
            f32x4 z = {0.f, 0.f, 0.f, 0.f};
            hacc[nt] = __builtin_amdgcn_mfma_f32_16x16x32_bf16(a1, bw1[nt], z, 0, 0, 0);
        }
        // relu + transpose via per-wave LDS
#pragma unroll
        for (int nt = 0; nt < 8; ++nt)
#pragma unroll
            for (int reg = 0; reg < 4; ++reg)
                hidW[(quad * 4 + reg) * 128 + nt * 16 + sl] = f2bf(fmaxf(hacc[nt][reg], 0.f));

        // layer 2
        f32x4 acc2 = {0.f, 0.f, 0.f, 0.f};
#pragma unroll
        for (int ks = 0; ks < 4; ++ks) {
            const bf16x8 a2 = *(const bf16x8*)&hidW[sl * 128 + ks * 32 + quad * 8];
            acc2 = __builtin_amdgcn_mfma_f32_16x16x32_bf16(a2, bw2[ks], acc2, 0, 0, 0);
        }

        // store logits: h = sl (<8), r = r0 + gmt>>1, c = c0 + (gmt&1)*16 + quad*4 + reg
        if (sl < 8) {
            const int r = r0 + (gmt >> 1);
            const int cbase = c0 + (gmt & 1) * 16 + quad * 4;
            float4 o; o.x = acc2[0]; o.y = acc2[1]; o.z = acc2[2]; o.w = acc2[3];
            *(float4*)&logits[((size_t)(b * 8 + sl) * 512 + r) * 512 + cbase] = o;
        }
    }
}

// ---------------------------------------------------------------------------
// Masked softmax over c (in-place on logits). One wave per row; 4 rows/block.
// ---------------------------------------------------------------------------
__global__ __launch_bounds__(256) void softmax_mask(float* __restrict__ logits,
                                                    const int* __restrict__ mask) {
    const int wave = threadIdx.x / 64;
    const int lane = threadIdx.x % 64;
    const size_t rowIdx = (size_t)blockIdx.x * 4 + wave;
    float* lp = logits + rowIdx * 512;
    const int* mp = mask + rowIdx * 512;

    float v[8];
    int   m[8];
    int allm = 1;
#pragma unroll
    for (int i = 0; i < 8; ++i) {
        v[i] = lp[lane + i * 64];
        m[i] = mp[lane + i * 64];
        allm &= (m[i] != 0);
    }
    const bool all_masked = (__all(allm) != 0);

    float mx = -__builtin_inff();
#pragma unroll
    for (int i = 0; i < 8; ++i) {
        const bool keep = all_masked || (m[i] == 0);
        if (keep) mx = fmaxf(mx, v[i]);
    }
#pragma unroll
    for (int s = 32; s > 0; s >>= 1) mx = fmaxf(mx, __shfl_xor(mx, s, 64));

    float e[8];
    float sum = 0.f;
#pragma unroll
    for (int i = 0; i < 8; ++i) {
        const bool keep = all_masked || (m[i] == 0);
        e[i] = keep ? __expf(v[i] - mx) : 0.f;
        sum += e[i];
    }
#pragma unroll
    for (int s = 32; s > 0; s >>= 1) sum += __shfl_xor(sum, s, 64);

    const float inv = 1.f / sum;
#pragma unroll
    for (int i = 0; i < 8; ++i) lp[lane + i * 64] = e[i] * inv;
}

// ---------------------------------------------------------------------------
// PV: per (b,h): Aout[b][r][h*64+d] = sum_c weights[b][h][r][c] * V[b][c][h*64+d]
// ---------------------------------------------------------------------------
__global__ __launch_bounds__(256) void pv_gemm(const float* __restrict__ Wt,
                                               const float* __restrict__ V,
                                               float* __restrict__ Aout) {
    __shared__ float Ws[16][64];
    __shared__ float Vs[16][64];
    const int bh = blockIdx.y;
    const int b = bh / 8, h = bh % 8;
    const int r0 = blockIdx.x * 64;
    const int t  = threadIdx.x;
    const int tm = t / 16, tn = t % 16;

    const float* wbase = Wt + ((size_t)bh) * 512 * 512;
    const float* vbase = V + (size_t)b * 512 * 512 + h * 64;

    float acc[4][4] = {};

    for (int c0 = 0; c0 < 512; c0 += 16) {
        {
            const int row = t / 4, c4 = t % 4;
            const float4 wv = *(const float4*)(wbase + (size_t)(r0 + row) * 512 + c0 + c4 * 4);
            Ws[c4 * 4 + 0][row] = wv.x;
            Ws[c4 * 4 + 1][row] = wv.y;
            Ws[c4 * 4 + 2][row] = wv.z;
            Ws[c4 * 4 + 3][row] = wv.w;
            const int vrow = t / 16, vc4 = t % 16;
            *(float4*)&Vs[vrow][vc4 * 4] =
                *(const float4*)(vbase + (size_t)(c0 + vrow) * 512 + vc4 * 4);
        }
        __syncthreads();
#pragma unroll
        for (int k = 0; k < 16; ++k) {
            const float4 a = *(const float4*)&Ws[k][tm * 4];
            const float4 bb = *(const float4*)&Vs[k][tn * 4];
            acc[0][0] += a.x * bb.x; acc[0][1] += a.x * bb.y; acc[0][2] += a.x * bb.z; acc[0][3] += a.x * bb.w;
            acc[1][0] += a.y * bb.x; acc[1][1] += a.y * bb.y; acc[1][2] += a.y * bb.z; acc[1][3] += a.y * bb.w;
            acc[2][0] += a.z * bb.x; acc[2][1] += a.z * bb.y; acc[2][2] += a.z * bb.z; acc[2][3] += a.z * bb.w;
            acc[3][0] += a.w * bb.x; acc[3][1] += a.w * bb.y; acc[3][2] += a.w * bb.z; acc[3][3] += a.w * bb.w;
        }
        __syncthreads();
    }
#pragma unroll
    for (int i = 0; i < 4; ++i)
#pragma unroll
        for (int j = 0; j < 4; ++j)
            Aout[((size_t)b * 512 + r0 + tm * 4 + i) * 512 + h * 64 + tn * 4 + j] = acc[i][j];
}

// ---------------------------------------------------------------------------
extern "C" void kernel_launch(void* const* d_in, const int* in_sizes, int n_in,
                              void* d_out, int out_size, void* d_ws, size_t ws_size,
                              hipStream_t stream) {
    const float* row_emb = (const float*)d_in[0];
    const float* col_emb = (const float*)d_in[1];
    const float* cost    = (const float*)d_in[2];
    const int*   mask    = (const int*)d_in[3];
    const float* Wq      = (const float*)d_in[4];
    const float* Wk      = (const float*)d_in[5];
    const float* Wv      = (const float*)d_in[6];
    const float* Wmix1   = (const float*)d_in[7];
    const float* Wmix2   = (const float*)d_in[8];
    const float* Wout    = (const float*)d_in[9];
    float* out = (float*)d_out;

    char* ws = (char*)d_ws;
    unsigned short* Qb = (unsigned short*)(ws);                      // 2 MB bf16 [b][r][h*64+d]
    unsigned short* Kb = (unsigned short*)(ws + ((size_t)2 << 20));  // 2 MB bf16 [b][c][h*64+d]
    float* V    = (float*)(ws + ((size_t)4  << 20));                 // 4 MB fp32
    float* Aout = (float*)(ws + ((size_t)8  << 20));                 // 4 MB fp32
    float* logitsBuf = (float*)(ws + ((size_t)16 << 20));            // 128 MB fp32 [b][h][r][c]

    dim3 g1(2048 / 64, 512 / 64);
    gemm_abt_bf16<<<g1, 256, 0, stream>>>(row_emb, Wq, Qb);
    gemm_abt_bf16<<<g1, 256, 0, stream>>>(col_emb, Wk, Kb);
    gemm_abt<<<g1, 256, 0, stream>>>(col_emb, Wv, V);

    dim3 g2(16, 16, 4);
    dot_mlp_mfma<<<g2, 256, 0, stream>>>(Qb, Kb, cost, Wmix1, Wmix2, logitsBuf);

    softmax_mask<<<4096, 256, 0, stream>>>(logitsBuf, mask);

    dim3 g4(8, 32);
    pv_gemm<<<g4, 256, 0, stream>>>(logitsBuf, V, Aout);

    gemm_abt<<<g1, 256, 0, stream>>>(Aout, Wout, out);
}

// Round 3
// 194.872 us; speedup vs baseline: 1.8008x; 1.5227x over previous
//
#include <hip/hip_runtime.h>
#include <math.h>

typedef __attribute__((ext_vector_type(8))) short bf16x8;
typedef __attribute__((ext_vector_type(4))) float f32x4;
typedef unsigned short ushort_t;

static __device__ inline unsigned short f2bf(float f) {
    union { float f; unsigned u; } v; v.f = f;
    unsigned r = v.u + 0x7fff + ((v.u >> 16) & 1);
    return (unsigned short)(r >> 16);
}

#if defined(__has_builtin)
#  if __has_builtin(__builtin_amdgcn_cvt_pk_bf16_f32)
#    define HAVE_PK_BF16 1
#  endif
#endif

// pack two floats -> two bf16 in one dword (lo = a, hi = b)
static __device__ inline unsigned pk2bf(float a, float b) {
#ifdef HAVE_PK_BF16
    auto r = __builtin_amdgcn_cvt_pk_bf16_f32(a, b);
    unsigned u; __builtin_memcpy(&u, &r, 4);
    return u;
#else
    return (unsigned)f2bf(a) | ((unsigned)f2bf(b) << 16);
#endif
}

// ---------------------------------------------------------------------------
// fp32 -> bf16 pre-convert of row_emb, col_emb, Wq, Wk, Wv, Wout into one
// contiguous bf16 region at ws[0]. Segment short-offsets:
// rowb 0 | colb 1048576 | Wqb 2097152 | Wkb 2359296 | Wvb 2621440 | Woutb 2883584
// total 3145728 elements.
// ---------------------------------------------------------------------------
__global__ __launch_bounds__(256) void convert_all(const float* __restrict__ a0,
                                                   const float* __restrict__ a1,
                                                   const float* __restrict__ a2,
                                                   const float* __restrict__ a3,
                                                   const float* __restrict__ a4,
                                                   const float* __restrict__ a5,
                                                   ushort_t* __restrict__ dst) {
    const size_t e = ((size_t)blockIdx.x * 256 + threadIdx.x) * 4;
    const float* src; size_t off;
    if      (e < 1048576) { src = a0; off = 0; }
    else if (e < 2097152) { src = a1; off = 1048576; }
    else if (e < 2359296) { src = a2; off = 2097152; }
    else if (e < 2621440) { src = a3; off = 2359296; }
    else if (e < 2883584) { src = a4; off = 2621440; }
    else                  { src = a5; off = 2883584; }
    const float4 v = *(const float4*)(src + (e - off));
    uint2 o; o.x = pk2bf(v.x, v.y); o.y = pk2bf(v.z, v.w);
    *(uint2*)(dst + e) = o;
}

// ---------------------------------------------------------------------------
// Direct-from-global bf16 MFMA GEMM: C[M][N] = A[M][K=512] @ B[N][K=512]^T.
// A, B bf16 row-major (ld = 512). Block 256 = 4 waves; tile 64x64;
// wave -> 32x32 via 2x2 16x16x32 MFMAs. No LDS: frags straight from L2.
// OM: 0 = bf16 C[m*512+n]; 1 = fp32 C[m*512+n]; 2 = Vt bf16 transposed store
//     Vt[((b*8+h)*64+d)*512 + c]  (m = b*512+c, n = h*64+d).
// ---------------------------------------------------------------------------
template<int OM>
__global__ __launch_bounds__(256) void gemm_bt(const ushort_t* __restrict__ A,
                                               const ushort_t* __restrict__ B,
                                               void* __restrict__ C) {
    const int t    = threadIdx.x;
    const int w    = t >> 6;
    const int lane = t & 63;
    const int quad = lane >> 4;
    const int sl   = lane & 15;
    const int m0 = blockIdx.x * 64 + (w >> 1) * 32;
    const int n0 = blockIdx.y * 64 + (w & 1) * 32;

    f32x4 acc[2][2] = {};

    for (int k0 = 0; k0 < 512; k0 += 32) {
        bf16x8 a[2], b[2];
#pragma unroll
        for (int rs = 0; rs < 2; ++rs)
            a[rs] = *(const bf16x8*)(A + (size_t)(m0 + rs * 16 + sl) * 512 + k0 + quad * 8);
#pragma unroll
        for (int cs = 0; cs < 2; ++cs)
            b[cs] = *(const bf16x8*)(B + (size_t)(n0 + cs * 16 + sl) * 512 + k0 + quad * 8);
#pragma unroll
        for (int rs = 0; rs < 2; ++rs)
#pragma unroll
            for (int cs = 0; cs < 2; ++cs)
                acc[rs][cs] = __builtin_amdgcn_mfma_f32_16x16x32_bf16(a[rs], b[cs], acc[rs][cs], 0, 0, 0);
    }

#pragma unroll
    for (int rs = 0; rs < 2; ++rs)
#pragma unroll
        for (int cs = 0; cs < 2; ++cs) {
            const int n = n0 + cs * 16 + sl;
            if (OM == 2) {
                // m = b*512 + c (c base multiple of 4), n = h*64+d
                const int mb   = m0 + rs * 16 + quad * 4;
                const int bidx = mb >> 9, c = mb & 511;
                const int h = n >> 6, d = n & 63;
                ushort4 o;
                o.x = f2bf(acc[rs][cs][0]); o.y = f2bf(acc[rs][cs][1]);
                o.z = f2bf(acc[rs][cs][2]); o.w = f2bf(acc[rs][cs][3]);
                *(ushort4*)((ushort_t*)C + (size_t)(((bidx * 8 + h) * 64 + d)) * 512 + c) = o;
            } else {
#pragma unroll
                for (int reg = 0; reg < 4; ++reg) {
                    const int m = m0 + rs * 16 + quad * 4 + reg;
                    if (OM == 0)
                        ((ushort_t*)C)[(size_t)m * 512 + n] = f2bf(acc[rs][cs][reg]);
                    else
                        ((float*)C)[(size_t)m * 512 + n] = acc[rs][cs][reg];
                }
            }
        }
}

// ---------------------------------------------------------------------------
// PV: per (b,h): Aout[b][r][h*64+d] (bf16) = P[bh][r][c] @ Vt[bh][d][c]^T.
// grid (8, 32). Same direct-global MFMA structure.
// ---------------------------------------------------------------------------
__global__ __launch_bounds__(256) void pv_bt(const ushort_t* __restrict__ P,
                                             const ushort_t* __restrict__ Vt,
                                             ushort_t* __restrict__ Aout) {
    const int t    = threadIdx.x;
    const int w    = t >> 6;
    const int lane = t & 63;
    const int quad = lane >> 4;
    const int sl   = lane & 15;
    const int bh = blockIdx.y;
    const int m0 = blockIdx.x * 64 + (w >> 1) * 32;
    const int n0 = (w & 1) * 32;

    const ushort_t* A = P  + (size_t)bh * 512 * 512;
    const ushort_t* B = Vt + (size_t)bh * 64 * 512;
    ushort_t* Cb = Aout + (size_t)(bh >> 3) * 512 * 512 + (bh & 7) * 64;

    f32x4 acc[2][2] = {};

    for (int k0 = 0; k0 < 512; k0 += 32) {
        bf16x8 a[2], b[2];
#pragma unroll
        for (int rs = 0; rs < 2; ++rs)
            a[rs] = *(const bf16x8*)(A + (size_t)(m0 + rs * 16 + sl) * 512 + k0 + quad * 8);
#pragma unroll
        for (int cs = 0; cs < 2; ++cs)
            b[cs] = *(const bf16x8*)(B + (size_t)(n0 + cs * 16 + sl) * 512 + k0 + quad * 8);
#pragma unroll
        for (int rs = 0; rs < 2; ++rs)
#pragma unroll
            for (int cs = 0; cs < 2; ++cs)
                acc[rs][cs] = __builtin_amdgcn_mfma_f32_16x16x32_bf16(a[rs], b[cs], acc[rs][cs], 0, 0, 0);
    }

#pragma unroll
    for (int rs = 0; rs < 2; ++rs)
#pragma unroll
        for (int cs = 0; cs < 2; ++cs) {
            const int n = n0 + cs * 16 + sl;
#pragma unroll
            for (int reg = 0; reg < 4; ++reg) {
                const int m = m0 + rs * 16 + quad * 4 + reg;
                Cb[(size_t)m * 512 + n] = f2bf(acc[rs][cs][reg]);
            }
        }
}

// ---------------------------------------------------------------------------
// dot + mixing MLP v3.
// grid (16,16,4), 256 threads. Tile 32r x 32c.
// Xs rows stride 18 shorts (conflict fix); hid rows stride 136 (b64 reads).
// ---------------------------------------------------------------------------
__global__ __launch_bounds__(256) void dot_mlp_v3(const ushort_t* __restrict__ Qb,
                                                  const ushort_t* __restrict__ Kb,
                                                  const float* __restrict__ cost,
                                                  const float* __restrict__ W1,
                                                  const float* __restrict__ W2,
                                                  float* __restrict__ logits) {
    __shared__ ushort_t Xs[1024 * 18];       // 36 KB, row stride 18
    __shared__ ushort_t hidS[4 * 16 * 136];  // 17 KB, per-wave 16x136
    __shared__ ushort_t W1fs[128 * 16];      // 4 KB
    __shared__ ushort_t W2ss[8 * 128];       // 2 KB

    const int b  = blockIdx.z;
    const int r0 = blockIdx.y * 32;
    const int c0 = blockIdx.x * 32;
    const int t    = threadIdx.x;
    const int w    = t >> 6;
    const int lane = t & 63;
    const int quad = lane >> 4;
    const int sl   = lane & 15;

    const bf16x8 zf = {0, 0, 0, 0, 0, 0, 0, 0};

    // --- zero Xs (covers the k=9..15 padding), stage weights ---
    {
        int4 z = {0, 0, 0, 0};
#pragma unroll
        for (int i = 0; i < 9; ++i) ((int4*)Xs)[t + i * 256] = z;
    }
    if (t < 128) {
        float s = 0.f;
#pragma unroll
        for (int h = 0; h < 8; ++h) {
            W1fs[t * 16 + h] = f2bf(W1[t * 16 + 2 * h]);
            s += W1[t * 16 + 2 * h + 1];
        }
        W1fs[t * 16 + 8] = f2bf(s);
#pragma unroll
        for (int k = 9; k < 16; ++k) W1fs[t * 16 + k] = 0;
    }
#pragma unroll
    for (int i = 0; i < 4; ++i) {
        const int idx = t + i * 256;
        W2ss[idx] = f2bf(W2[idx]);
    }
    __syncthreads();

    // --- cost -> X[cell][8] ---
#pragma unroll
    for (int i = 0; i < 4; ++i) {
        const int cell = t + i * 256;
        const int rl = cell >> 5, cl = cell & 31;
        Xs[cell * 18 + 8] = f2bf(cost[((size_t)b * 512 + r0 + rl) * 512 + c0 + cl]);
    }

    // --- Phase A: dots for heads 2w, 2w+1, straight from global bf16 ---
    f32x4 dacc[2][2][2];
#pragma unroll
    for (int hh = 0; hh < 2; ++hh) {
        const int h = 2 * w + hh;
        bf16x8 af[2][2], bfr[2][2];
#pragma unroll
        for (int rs = 0; rs < 2; ++rs)
#pragma unroll
            for (int ks = 0; ks < 2; ++ks)
                af[rs][ks] = *(const bf16x8*)(Qb +
                    ((size_t)(b * 512 + r0 + rs * 16 + sl) * 512 + h * 64 + ks * 32 + quad * 8));
#pragma unroll
        for (int cs = 0; cs < 2; ++cs)
#pragma unroll
            for (int ks = 0; ks < 2; ++ks)
                bfr[cs][ks] = *(const bf16x8*)(Kb +
                    ((size_t)(b * 512 + c0 + cs * 16 + sl) * 512 + h * 64 + ks * 32 + quad * 8));
#pragma unroll
        for (int rs = 0; rs < 2; ++rs)
#pragma unroll
            for (int cs = 0; cs < 2; ++cs) {
                f32x4 acc = {0.f, 0.f, 0.f, 0.f};
                acc = __builtin_amdgcn_mfma_f32_16x16x32_bf16(af[rs][0], bfr[cs][0], acc, 0, 0, 0);
                acc = __builtin_amdgcn_mfma_f32_16x16x32_bf16(af[rs][1], bfr[cs][1], acc, 0, 0, 0);
                dacc[hh][rs][cs] = acc;
            }
    }
    // packed write: heads (2w, 2w+1) -> dword w of the cell's X row
#pragma unroll
    for (int rs = 0; rs < 2; ++rs)
#pragma unroll
        for (int cs = 0; cs < 2; ++cs)
#pragma unroll
            for (int reg = 0; reg < 4; ++reg) {
                const int cell = (rs * 16 + quad * 4 + reg) * 32 + cs * 16 + sl;
                ((unsigned*)Xs)[cell * 9 + w] =
                    pk2bf(dacc[0][rs][cs][reg] * 0.125f, dacc[1][rs][cs][reg] * 0.125f);
            }

    __syncthreads();

    // --- Phase B ---
    bf16x8 bw1[8];
#pragma unroll
    for (int nt = 0; nt < 8; ++nt)
        bw1[nt] = (quad < 2) ? *(const bf16x8*)&W1fs[(nt * 16 + sl) * 16 + quad * 8] : zf;
    bf16x8 bw2[4];
#pragma unroll
    for (int ks = 0; ks < 4; ++ks)
        bw2[ks] = (sl < 8) ? *(const bf16x8*)&W2ss[sl * 128 + ks * 32 + quad * 8] : zf;

    ushort_t* hidW = hidS + w * (16 * 136);

    for (int mt = 0; mt < 16; ++mt) {
        const int gmt = w * 16 + mt;  // 0..63
        const int cb  = gmt * 16;

        // layer 1: A = X rows (4x b32 reads, stride-18 rows)
        bf16x8 a1 = zf;
        if (quad < 2) {
            const unsigned* xr = (const unsigned*)Xs + (size_t)(cb + sl) * 9 + quad * 4;
            union { unsigned u[4]; bf16x8 v; } tmp;
            tmp.u[0] = xr[0]; tmp.u[1] = xr[1]; tmp.u[2] = xr[2]; tmp.u[3] = xr[3];
            a1 = tmp.v;
        }
        f32x4 hacc[8];
#pragma unroll
        for (int nt = 0; nt < 8; ++nt) {
            f32x4 z = {0.f, 0.f, 0.f, 0.f};
            hacc[nt] = __builtin_amdgcn_mfma_f32_16x16x32_bf16(a1, bw1[nt], z, 0, 0, 0);
        }
        // relu + packed cvt + transpose into wave-private hid (stride 136)
#pragma unroll
        for (int nt = 0; nt < 8; ++nt)
#pragma unroll
            for (int rp = 0; rp < 4; rp += 2) {
                const unsigned u = pk2bf(fmaxf(hacc[nt][rp], 0.f), fmaxf(hacc[nt][rp + 1], 0.f));
                hidW[(quad * 4 + rp) * 136 + nt * 16 + sl]     = (ushort_t)u;
                hidW[(quad * 4 + rp + 1) * 136 + nt * 16 + sl] = (ushort_t)(u >> 16);
            }

        // layer 2 (b64 reads)
        f32x4 acc2 = {0.f, 0.f, 0.f, 0.f};
#pragma unroll
        for (int ks = 0; ks < 4; ++ks) {
            const ushort_t* hp = hidW + sl * 136 + ks * 32 + quad * 8;
            union { unsigned u[4]; bf16x8 v; } tu;
            *(uint2*)&tu.u[0] = *(const uint2*)hp;
            *(uint2*)&tu.u[2] = *(const uint2*)(hp + 4);
            acc2 = __builtin_amdgcn_mfma_f32_16x16x32_bf16(tu.v, bw2[ks], acc2, 0, 0, 0);
        }

        if (sl < 8) {
            const int r = r0 + (gmt >> 1);
            const int cbase = c0 + (gmt & 1) * 16 + quad * 4;
            float4 o; o.x = acc2[0]; o.y = acc2[1]; o.z = acc2[2]; o.w = acc2[3];
            *(float4*)&logits[((size_t)(b * 8 + sl) * 512 + r) * 512 + cbase] = o;
        }
    }
}

// ---------------------------------------------------------------------------
// Masked softmax: fp32 logits in, bf16 weights out. One wave per row.
// ---------------------------------------------------------------------------
__global__ __launch_bounds__(256) void softmax_mask(const float* __restrict__ logits,
                                                    const int* __restrict__ mask,
                                                    ushort_t* __restrict__ Pb) {
    const int wave = threadIdx.x / 64;
    const int lane = threadIdx.x % 64;
    const size_t rowIdx = (size_t)blockIdx.x * 4 + wave;
    const float* lp = logits + rowIdx * 512;
    const int* mp = mask + rowIdx * 512;

    float v[8];
    int   m[8];
    int allm = 1;
#pragma unroll
    for (int i = 0; i < 8; ++i) {
        v[i] = lp[lane + i * 64];
        m[i] = mp[lane + i * 64];
        allm &= (m[i] != 0);
    }
    const bool all_masked = (__all(allm) != 0);

    float mx = -__builtin_inff();
#pragma unroll
    for (int i = 0; i < 8; ++i) {
        const bool keep = all_masked || (m[i] == 0);
        if (keep) mx = fmaxf(mx, v[i]);
    }
#pragma unroll
    for (int s = 32; s > 0; s >>= 1) mx = fmaxf(mx, __shfl_xor(mx, s, 64));

    float e[8];
    float sum = 0.f;
#pragma unroll
    for (int i = 0; i < 8; ++i) {
        const bool keep = all_masked || (m[i] == 0);
        e[i] = keep ? __expf(v[i] - mx) : 0.f;
        sum += e[i];
    }
#pragma unroll
    for (int s = 32; s > 0; s >>= 1) sum += __shfl_xor(sum, s, 64);

    const float inv = 1.f / sum;
#pragma unroll
    for (int i = 0; i < 8; ++i)
        Pb[rowIdx * 512 + lane + i * 64] = f2bf(e[i] * inv);
}

// ---------------------------------------------------------------------------
extern "C" void kernel_launch(void* const* d_in, const int* in_sizes, int n_in,
                              void* d_out, int out_size, void* d_ws, size_t ws_size,
                              hipStream_t stream) {
    const float* row_emb = (const float*)d_in[0];
    const float* col_emb = (const float*)d_in[1];
    const float* cost    = (const float*)d_in[2];
    const int*   mask    = (const int*)d_in[3];
    const float* Wq      = (const float*)d_in[4];
    const float* Wk      = (const float*)d_in[5];
    const float* Wv      = (const float*)d_in[6];
    const float* Wmix1   = (const float*)d_in[7];
    const float* Wmix2   = (const float*)d_in[8];
    const float* Wout    = (const float*)d_in[9];
    float* out = (float*)d_out;

    char* ws = (char*)d_ws;
    const size_t MB = (size_t)1 << 20;
    ushort_t* convDst = (ushort_t*)ws;                        // 6 MB bf16 region
    ushort_t* rowb  = (ushort_t*)(ws);                        // shorts 0..
    ushort_t* colb  = (ushort_t*)(ws + 2 * MB);
    ushort_t* Wqb   = (ushort_t*)(ws + 4 * MB);
    ushort_t* Wkb   = (ushort_t*)(ws + 4 * MB + 512 * 1024);
    ushort_t* Wvb   = (ushort_t*)(ws + 5 * MB);
    ushort_t* Woutb = (ushort_t*)(ws + 5 * MB + 512 * 1024);
    ushort_t* Qb    = (ushort_t*)(ws + 6 * MB);               // [b*512+r][512]
    ushort_t* Kb    = (ushort_t*)(ws + 8 * MB);
    ushort_t* Vt    = (ushort_t*)(ws + 10 * MB);              // [bh][d][c]
    ushort_t* Aoutb = (ushort_t*)(ws + 12 * MB);              // [b*512+r][512]
    ushort_t* Pb    = (ushort_t*)(ws + 16 * MB);              // [bh][r][c] 16.8 MB
    float* logitsBuf = (float*)(ws + 40 * MB);                // 33.6 MB

    convert_all<<<3072, 256, 0, stream>>>(row_emb, col_emb, Wq, Wk, Wv, Wout, convDst);

    dim3 g1(32, 8);
    gemm_bt<0><<<g1, 256, 0, stream>>>(rowb, Wqb, Qb);
    gemm_bt<0><<<g1, 256, 0, stream>>>(colb, Wkb, Kb);
    gemm_bt<2><<<g1, 256, 0, stream>>>(colb, Wvb, Vt);

    dim3 g2(16, 16, 4);
    dot_mlp_v3<<<g2, 256, 0, stream>>>(Qb, Kb, cost, Wmix1, Wmix2, logitsBuf);

    softmax_mask<<<4096, 256, 0, stream>>>(logitsBuf, mask, Pb);

    pv_bt<<<dim3(8, 32), 256, 0, stream>>>(Pb, Vt, Aoutb);

    gemm_bt<1><<<g1, 256, 0, stream>>>(Aoutb, Woutb, out);
}

// Round 5
// 186.847 us; speedup vs baseline: 1.8781x; 1.0429x over previous
//
#include <hip/hip_runtime.h>
#include <math.h>

typedef __attribute__((ext_vector_type(8))) short bf16x8;
typedef __attribute__((ext_vector_type(4))) float f32x4;
typedef unsigned short ushort_t;

static __device__ inline unsigned short f2bf(float f) {
    union { float f; unsigned u; } v; v.f = f;
    unsigned r = v.u + 0x7fff + ((v.u >> 16) & 1);
    return (unsigned short)(r >> 16);
}

#if defined(__has_builtin)
#  if __has_builtin(__builtin_amdgcn_cvt_pk_bf16_f32)
#    define HAVE_PK_BF16 1
#  endif
#endif

static __device__ inline unsigned pk2bf(float a, float b) {
#ifdef HAVE_PK_BF16
    auto r = __builtin_amdgcn_cvt_pk_bf16_f32(a, b);
    unsigned u; __builtin_memcpy(&u, &r, 4);
    return u;
#else
    return (unsigned)f2bf(a) | ((unsigned)f2bf(b) << 16);
#endif
}

// ---------------------------------------------------------------------------
// fp32 -> bf16 pre-convert (row_emb, col_emb, Wq, Wk, Wv, Wout) -> ws bf16.
// ---------------------------------------------------------------------------
__global__ __launch_bounds__(256) void convert_all(const float* __restrict__ a0,
                                                   const float* __restrict__ a1,
                                                   const float* __restrict__ a2,
                                                   const float* __restrict__ a3,
                                                   const float* __restrict__ a4,
                                                   const float* __restrict__ a5,
                                                   ushort_t* __restrict__ dst) {
    const size_t e = ((size_t)blockIdx.x * 256 + threadIdx.x) * 4;
    const float* src; size_t off;
    if      (e < 1048576) { src = a0; off = 0; }
    else if (e < 2097152) { src = a1; off = 1048576; }
    else if (e < 2359296) { src = a2; off = 2097152; }
    else if (e < 2621440) { src = a3; off = 2359296; }
    else if (e < 2883584) { src = a4; off = 2621440; }
    else                  { src = a5; off = 2883584; }
    const float4 v = *(const float4*)(src + (e - off));
    uint2 o; o.x = pk2bf(v.x, v.y); o.y = pk2bf(v.z, v.w);
    *(uint2*)(dst + e) = o;
}

// ---------------------------------------------------------------------------
// Q/K/V projections in one launch. z=0: Q=rowb@Wq^T (bf16 rows out);
// z=1: K=colb@Wk^T; z=2: V=colb@Wv^T stored transposed Vt[bh][d][c].
// ---------------------------------------------------------------------------
__global__ __launch_bounds__(256) void gemm_qkv(const ushort_t* __restrict__ rowb,
                                                const ushort_t* __restrict__ colb,
                                                const ushort_t* __restrict__ Wqb,
                                                const ushort_t* __restrict__ Wkb,
                                                const ushort_t* __restrict__ Wvb,
                                                ushort_t* __restrict__ Qb,
                                                ushort_t* __restrict__ Kb,
                                                ushort_t* __restrict__ Vt) {
    const int z = blockIdx.z;
    const ushort_t* A = (z == 0) ? rowb : colb;
    const ushort_t* B = (z == 0) ? Wqb : (z == 1) ? Wkb : Wvb;

    const int t    = threadIdx.x;
    const int w    = t >> 6;
    const int lane = t & 63;
    const int quad = lane >> 4;
    const int sl   = lane & 15;
    const int m0 = blockIdx.x * 64 + (w >> 1) * 32;
    const int n0 = blockIdx.y * 64 + (w & 1) * 32;

    f32x4 acc[2][2] = {};

    for (int k0 = 0; k0 < 512; k0 += 32) {
        bf16x8 a[2], b[2];
#pragma unroll
        for (int rs = 0; rs < 2; ++rs)
            a[rs] = *(const bf16x8*)(A + (size_t)(m0 + rs * 16 + sl) * 512 + k0 + quad * 8);
#pragma unroll
        for (int cs = 0; cs < 2; ++cs)
            b[cs] = *(const bf16x8*)(B + (size_t)(n0 + cs * 16 + sl) * 512 + k0 + quad * 8);
#pragma unroll
        for (int rs = 0; rs < 2; ++rs)
#pragma unroll
            for (int cs = 0; cs < 2; ++cs)
                acc[rs][cs] = __builtin_amdgcn_mfma_f32_16x16x32_bf16(a[rs], b[cs], acc[rs][cs], 0, 0, 0);
    }

#pragma unroll
    for (int rs = 0; rs < 2; ++rs)
#pragma unroll
        for (int cs = 0; cs < 2; ++cs) {
            const int n = n0 + cs * 16 + sl;
            if (z == 2) {
                const int mb   = m0 + rs * 16 + quad * 4;
                const int bidx = mb >> 9, c = mb & 511;
                const int h = n >> 6, d = n & 63;
                ushort4 o;
                o.x = f2bf(acc[rs][cs][0]); o.y = f2bf(acc[rs][cs][1]);
                o.z = f2bf(acc[rs][cs][2]); o.w = f2bf(acc[rs][cs][3]);
                *(ushort4*)(Vt + (size_t)(((bidx * 8 + h) * 64 + d)) * 512 + c) = o;
            } else {
                ushort_t* C = (z == 0) ? Qb : Kb;
#pragma unroll
                for (int reg = 0; reg < 4; ++reg) {
                    const int m = m0 + rs * 16 + quad * 4 + reg;
                    C[(size_t)m * 512 + n] = f2bf(acc[rs][cs][reg]);
                }
            }
        }
}

// ---------------------------------------------------------------------------
// Final GEMM: out[M][512] = Aoutb @ Woutb^T, fp32 out.
// ---------------------------------------------------------------------------
__global__ __launch_bounds__(256) void gemm_out(const ushort_t* __restrict__ A,
                                                const ushort_t* __restrict__ B,
                                                float* __restrict__ C) {
    const int t    = threadIdx.x;
    const int w    = t >> 6;
    const int lane = t & 63;
    const int quad = lane >> 4;
    const int sl   = lane & 15;
    const int m0 = blockIdx.x * 64 + (w >> 1) * 32;
    const int n0 = blockIdx.y * 64 + (w & 1) * 32;

    f32x4 acc[2][2] = {};

    for (int k0 = 0; k0 < 512; k0 += 32) {
        bf16x8 a[2], b[2];
#pragma unroll
        for (int rs = 0; rs < 2; ++rs)
            a[rs] = *(const bf16x8*)(A + (size_t)(m0 + rs * 16 + sl) * 512 + k0 + quad * 8);
#pragma unroll
        for (int cs = 0; cs < 2; ++cs)
            b[cs] = *(const bf16x8*)(B + (size_t)(n0 + cs * 16 + sl) * 512 + k0 + quad * 8);
#pragma unroll
        for (int rs = 0; rs < 2; ++rs)
#pragma unroll
            for (int cs = 0; cs < 2; ++cs)
                acc[rs][cs] = __builtin_amdgcn_mfma_f32_16x16x32_bf16(a[rs], b[cs], acc[rs][cs], 0, 0, 0);
    }

#pragma unroll
    for (int rs = 0; rs < 2; ++rs)
#pragma unroll
        for (int cs = 0; cs < 2; ++cs) {
            const int n = n0 + cs * 16 + sl;
#pragma unroll
            for (int reg = 0; reg < 4; ++reg) {
                const int m = m0 + rs * 16 + quad * 4 + reg;
                C[(size_t)m * 512 + n] = acc[rs][cs][reg];
            }
        }
}

// ---------------------------------------------------------------------------
// dot + mixing MLP v4: 512 threads (8 waves), 32x32 tile, grid (16,16,4).
// Phase A: wave w computes head h=w dots for all 1024 cells -> Xs.
// Phase B: per wave 8 m-tiles (8 waves x 8 x 16 cells = 1024 = full tile);
// layer1/layer2 interleaved per 32-k-chunk with a k-permuted hid layout.
// ---------------------------------------------------------------------------
__global__ __launch_bounds__(512) void dot_mlp_v4(const ushort_t* __restrict__ Qb,
                                                  const ushort_t* __restrict__ Kb,
                                                  const float* __restrict__ cost,
                                                  const float* __restrict__ W1,
                                                  const float* __restrict__ W2,
                                                  float* __restrict__ logits) {
    __shared__ ushort_t Xs[1024 * 18];      // 36 KB, row stride 18 shorts
    __shared__ ushort_t hidS[8 * 16 * 36];  // 9 KB, per-wave 16x36 shorts
    __shared__ ushort_t W1fs[128 * 16];     // 4 KB
    __shared__ ushort_t W2ss[8 * 128];      // 2 KB

    const int b  = blockIdx.z;
    const int r0 = blockIdx.y * 32;
    const int c0 = blockIdx.x * 32;
    const int t    = threadIdx.x;
    const int w    = t >> 6;
    const int lane = t & 63;
    const int quad = lane >> 4;
    const int sl   = lane & 15;

    const bf16x8 zf = {0, 0, 0, 0, 0, 0, 0, 0};

    // --- stage weights ---
    if (t < 128) {
        float s = 0.f;
#pragma unroll
        for (int h = 0; h < 8; ++h) {
            W1fs[t * 16 + h] = f2bf(W1[t * 16 + 2 * h]);
            s += W1[t * 16 + 2 * h + 1];
        }
        W1fs[t * 16 + 8] = f2bf(s);
#pragma unroll
        for (int k = 9; k < 16; ++k) W1fs[t * 16 + k] = 0;
    }
#pragma unroll
    for (int i = 0; i < 2; ++i) W2ss[t + i * 512] = f2bf(W2[t + i * 512]);

    // --- cost -> X slot 8; zero slots 9..17 ---
#pragma unroll
    for (int i = 0; i < 2; ++i) {
        const int cell = t + i * 512;
        const int rl = cell >> 5, cl = cell & 31;
        unsigned* base = (unsigned*)(Xs + cell * 18 + 8);  // dword-aligned
        base[0] = (unsigned)f2bf(cost[((size_t)b * 512 + r0 + rl) * 512 + c0 + cl]);
        base[1] = 0; base[2] = 0; base[3] = 0; base[4] = 0;
    }

    // --- Phase A: head h = w ---
    {
        const int h = w;
        bf16x8 af[2][2], bfr[2][2];
#pragma unroll
        for (int rs = 0; rs < 2; ++rs)
#pragma unroll
            for (int ks = 0; ks < 2; ++ks)
                af[rs][ks] = *(const bf16x8*)(Qb +
                    ((size_t)(b * 512 + r0 + rs * 16 + sl) * 512 + h * 64 + ks * 32 + quad * 8));
#pragma unroll
        for (int cs = 0; cs < 2; ++cs)
#pragma unroll
            for (int ks = 0; ks < 2; ++ks)
                bfr[cs][ks] = *(const bf16x8*)(Kb +
                    ((size_t)(b * 512 + c0 + cs * 16 + sl) * 512 + h * 64 + ks * 32 + quad * 8));
#pragma unroll
        for (int rs = 0; rs < 2; ++rs)
#pragma unroll
            for (int cs = 0; cs < 2; ++cs) {
                f32x4 acc = {0.f, 0.f, 0.f, 0.f};
                acc = __builtin_amdgcn_mfma_f32_16x16x32_bf16(af[rs][0], bfr[cs][0], acc, 0, 0, 0);
                acc = __builtin_amdgcn_mfma_f32_16x16x32_bf16(af[rs][1], bfr[cs][1], acc, 0, 0, 0);
#pragma unroll
                for (int reg = 0; reg < 4; ++reg) {
                    const int cell = (rs * 16 + quad * 4 + reg) * 32 + cs * 16 + sl;
                    Xs[cell * 18 + h] = f2bf(acc[reg] * 0.125f);
                }
            }
    }

    __syncthreads();

    // --- Phase B ---
    bf16x8 bw1[8];
#pragma unroll
    for (int nt = 0; nt < 8; ++nt)
        bw1[nt] = (quad < 2) ? *(const bf16x8*)&W1fs[(nt * 16 + sl) * 16 + quad * 8] : zf;
    // W2 frags with permuted k: phys p -> j_chunk = (p>>1) | ((p&1)<<4)
    bf16x8 bw2[4];
#pragma unroll
    for (int ks = 0; ks < 4; ++ks) {
        union { ushort_t s[8]; bf16x8 v; } tu;
#pragma unroll
        for (int i = 0; i < 8; ++i) {
            const int p  = quad * 8 + i;
            const int jc = (p >> 1) | ((p & 1) << 4);
            tu.s[i] = (sl < 8) ? W2ss[sl * 128 + ks * 32 + jc] : (ushort_t)0;
        }
        bw2[ks] = tu.v;
    }

    ushort_t* hidW = hidS + w * (16 * 36);

#pragma unroll
    for (int mt = 0; mt < 8; ++mt) {
        const int gmt = w * 8 + mt;   // 0..63  (8 waves x 8 = full 64 m-tiles)
        const int cb  = gmt * 16;

        bf16x8 a1 = zf;
        if (quad < 2) {
            const unsigned* xr = (const unsigned*)Xs + (size_t)(cb + sl) * 9 + quad * 4;
            union { unsigned u[4]; bf16x8 v; } tmp;
            tmp.u[0] = xr[0]; tmp.u[1] = xr[1]; tmp.u[2] = xr[2]; tmp.u[3] = xr[3];
            a1 = tmp.v;
        }

        f32x4 acc2 = {0.f, 0.f, 0.f, 0.f};
#pragma unroll
        for (int ks = 0; ks < 4; ++ks) {
            f32x4 z = {0.f, 0.f, 0.f, 0.f};
            const f32x4 h0 = __builtin_amdgcn_mfma_f32_16x16x32_bf16(a1, bw1[2 * ks],     z, 0, 0, 0);
            const f32x4 h1 = __builtin_amdgcn_mfma_f32_16x16x32_bf16(a1, bw1[2 * ks + 1], z, 0, 0, 0);
#pragma unroll
            for (int rp = 0; rp < 4; ++rp)
                ((unsigned*)hidW)[(quad * 4 + rp) * 18 + sl] =
                    pk2bf(fmaxf(h0[rp], 0.f), fmaxf(h1[rp], 0.f));
            union { uint2 u2[2]; bf16x8 v; } tu;
            const ushort_t* hp = hidW + sl * 36 + quad * 8;
            tu.u2[0] = *(const uint2*)hp;
            tu.u2[1] = *(const uint2*)(hp + 4);
            acc2 = __builtin_amdgcn_mfma_f32_16x16x32_bf16(tu.v, bw2[ks], acc2, 0, 0, 0);
        }

        if (sl < 8) {
            const int r = r0 + (gmt >> 1);
            const int cbase = c0 + (gmt & 1) * 16 + quad * 4;
            float4 o; o.x = acc2[0]; o.y = acc2[1]; o.z = acc2[2]; o.w = acc2[3];
            *(float4*)&logits[((size_t)(b * 8 + sl) * 512 + r) * 512 + cbase] = o;
        }
    }
}

// ---------------------------------------------------------------------------
// Fused masked-softmax + PV. grid (16 r-tiles, 32 bh), 256 threads (4 waves).
// ---------------------------------------------------------------------------
__global__ __launch_bounds__(256) void softmax_pv(const float* __restrict__ logits,
                                                  const int* __restrict__ mask,
                                                  const ushort_t* __restrict__ Vt,
                                                  ushort_t* __restrict__ Aout) {
    __shared__ ushort_t Ps[32 * 520];   // 33.3 KB, row stride 520 shorts

    const int t    = threadIdx.x;
    const int w    = t >> 6;
    const int lane = t & 63;
    const int quad = lane >> 4;
    const int sl   = lane & 15;
    const int rt = blockIdx.x;
    const int bh = blockIdx.y;
    const int r0 = rt * 32;

    // --- softmax: 8 rows per wave ---
#pragma unroll
    for (int rr = 0; rr < 8; ++rr) {
        const int row = w * 8 + rr;
        const float* lp = logits + ((size_t)bh * 512 + r0 + row) * 512;
        const int*   mp = mask   + ((size_t)bh * 512 + r0 + row) * 512;

        float v[8]; int m[8]; int allm = 1;
#pragma unroll
        for (int i = 0; i < 8; ++i) {
            v[i] = lp[lane + i * 64];
            m[i] = mp[lane + i * 64];
            allm &= (m[i] != 0);
        }
        const bool all_masked = (__all(allm) != 0);

        float mx = -__builtin_inff();
#pragma unroll
        for (int i = 0; i < 8; ++i) {
            const bool keep = all_masked || (m[i] == 0);
            if (keep) mx = fmaxf(mx, v[i]);
        }
#pragma unroll
        for (int s = 32; s > 0; s >>= 1) mx = fmaxf(mx, __shfl_xor(mx, s, 64));

        float e[8]; float sum = 0.f;
#pragma unroll
        for (int i = 0; i < 8; ++i) {
            const bool keep = all_masked || (m[i] == 0);
            e[i] = keep ? __expf(v[i] - mx) : 0.f;
            sum += e[i];
        }
#pragma unroll
        for (int s = 32; s > 0; s >>= 1) sum += __shfl_xor(sum, s, 64);

        const float inv = 1.f / sum;
#pragma unroll
        for (int i = 0; i < 8; ++i)
            Ps[row * 520 + lane + i * 64] = f2bf(e[i] * inv);
    }

    __syncthreads();

    // --- PV ---
    const int mt  = w >> 1;
    const int n0w = (w & 1) * 32;
    const ushort_t* vb = Vt + (size_t)bh * 64 * 512;

    f32x4 acc[2] = {};
    for (int ks = 0; ks < 16; ++ks) {
        union { uint2 u2[2]; bf16x8 v; } ta;
        const ushort_t* pp = Ps + (size_t)(mt * 16 + sl) * 520 + ks * 32 + quad * 8;
        ta.u2[0] = *(const uint2*)pp;
        ta.u2[1] = *(const uint2*)(pp + 4);
        bf16x8 bv[2];
#pragma unroll
        for (int cn = 0; cn < 2; ++cn)
            bv[cn] = *(const bf16x8*)(vb + (size_t)(n0w + cn * 16 + sl) * 512 + ks * 32 + quad * 8);
#pragma unroll
        for (int cn = 0; cn < 2; ++cn)
            acc[cn] = __builtin_amdgcn_mfma_f32_16x16x32_bf16(ta.v, bv[cn], acc[cn], 0, 0, 0);
    }

    const int bidx = bh >> 3, h = bh & 7;
    ushort_t* Cb = Aout + (size_t)bidx * 512 * 512 + h * 64;
#pragma unroll
    for (int cn = 0; cn < 2; ++cn) {
        const int n = n0w + cn * 16 + sl;
#pragma unroll
        for (int reg = 0; reg < 4; ++reg) {
            const int m = r0 + mt * 16 + quad * 4 + reg;
            Cb[(size_t)m * 512 + n] = f2bf(acc[cn][reg]);
        }
    }
}

// ---------------------------------------------------------------------------
extern "C" void kernel_launch(void* const* d_in, const int* in_sizes, int n_in,
                              void* d_out, int out_size, void* d_ws, size_t ws_size,
                              hipStream_t stream) {
    const float* row_emb = (const float*)d_in[0];
    const float* col_emb = (const float*)d_in[1];
    const float* cost    = (const float*)d_in[2];
    const int*   mask    = (const int*)d_in[3];
    const float* Wq      = (const float*)d_in[4];
    const float* Wk      = (const float*)d_in[5];
    const float* Wv      = (const float*)d_in[6];
    const float* Wmix1   = (const float*)d_in[7];
    const float* Wmix2   = (const float*)d_in[8];
    const float* Wout    = (const float*)d_in[9];
    float* out = (float*)d_out;

    char* ws = (char*)d_ws;
    const size_t MB = (size_t)1 << 20;
    ushort_t* convDst = (ushort_t*)ws;
    ushort_t* rowb  = (ushort_t*)(ws);
    ushort_t* colb  = (ushort_t*)(ws + 2 * MB);
    ushort_t* Wqb   = (ushort_t*)(ws + 4 * MB);
    ushort_t* Wkb   = (ushort_t*)(ws + 4 * MB + 512 * 1024);
    ushort_t* Wvb   = (ushort_t*)(ws + 5 * MB);
    ushort_t* Woutb = (ushort_t*)(ws + 5 * MB + 512 * 1024);
    ushort_t* Qb    = (ushort_t*)(ws + 6 * MB);   // bf16 [b*512+r][512]
    ushort_t* Kb    = (ushort_t*)(ws + 8 * MB);
    ushort_t* Vt    = (ushort_t*)(ws + 10 * MB);  // bf16 [bh][d][c]
    ushort_t* Aoutb = (ushort_t*)(ws + 12 * MB);  // bf16 [b*512+r][512]
    float* logitsBuf = (float*)(ws + 40 * MB);    // fp32 [bh][r][c] 33.6 MB

    convert_all<<<3072, 256, 0, stream>>>(row_emb, col_emb, Wq, Wk, Wv, Wout, convDst);

    gemm_qkv<<<dim3(32, 8, 3), 256, 0, stream>>>(rowb, colb, Wqb, Wkb, Wvb, Qb, Kb, Vt);

    dot_mlp_v4<<<dim3(16, 16, 4), 512, 0, stream>>>(Qb, Kb, cost, Wmix1, Wmix2, logitsBuf);

    softmax_pv<<<dim3(16, 32), 256, 0, stream>>>(logitsBuf, mask, Vt, Aoutb);

    gemm_out<<<dim3(32, 8), 256, 0, stream>>>(Aoutb, Woutb, out);
}